// Round 9
// baseline (729.216 us; speedup 1.0000x reference)
//
#include <hip/hip_runtime.h>

#define J 17
#define JP 18             // padded inner dim (2-way LDS bank alias = free)
#define VO 289            // 17*17
#define NB 8192
#define DIN 2048
#define EPSB 1e-5f
#define KC 1024           // conv0: k-floats per staged chunk (4KB per row)
#define RT 16             // conv0: rows per block
#define NCH 34            // 17*2048/1024 chunks per row

typedef __attribute__((ext_vector_type(8))) short bf16x8;
typedef __attribute__((ext_vector_type(4))) float f32x4;

// adjacency (incl. self) as bitmasks, from SKEL
__device__ __constant__ unsigned ADJM[J] = {
  0x7u, 0xFu, 0x17u, 0x2Au, 0x54u, 0x8E8u, 0x1170u, 0x2A0u, 0x540u,
  0x280u, 0x500u, 0x3820u, 0x5840u, 0xA800u, 0x15000u, 0xA000u, 0x14000u};

__device__ inline unsigned short f2bf(float x){
  unsigned u = __float_as_uint(x);
  return (unsigned short)((u + 0x7fffu + ((u>>16)&1u)) >> 16);   // RNE
}

__global__ void zero_stats(float* p, int n) {
  int i = blockIdx.x*blockDim.x + threadIdx.x;
  int stride = gridDim.x*blockDim.x;
  for (; i < n; i += stride) p[i] = 0.f;
}

// -------- prepass: W0 [17][2048][17] f32 -> Wbt [17][32 cols][2048 k] bf16 (cols 17..31 zero)
__global__ __launch_bounds__(256) void wconv_kernel(
    const float* __restrict__ W0, unsigned short* __restrict__ Wbt)
{
  int t = blockIdx.x*256 + threadIdx.x;    // t = v*2048 + k
  int v = t >> 11, k = t & 2047;
  const float* src = W0 + (size_t)t*J;
  unsigned short* dst = Wbt + ((size_t)v*32 << 11) + k;
  #pragma unroll
  for (int o=0;o<J;++o)  dst[(size_t)o<<11] = f2bf(src[o]);
  #pragma unroll
  for (int o=J;o<32;++o) dst[(size_t)o<<11] = 0;
}

// -------- conv0 v3 (round-7 verbatim): streaming per-row GEMM, 4KB runs.
__global__ __launch_bounds__(256) void conv0_kernel(
    const float* __restrict__ feat, const unsigned short* __restrict__ Wbt,
    const float* __restrict__ b0, float* __restrict__ C,
    float* __restrict__ stat0)
{
  const int tid = threadIdx.x, w = tid>>6, l = tid&63;
  const int lo = l&15, oc = l>>4;
  const int sr = tid>>4, sc = tid&15;       // staging: row, col-group
  const int rowBase = blockIdx.x*RT;

  __shared__ __align__(16) unsigned short Ab[2][RT*KC];   // 64 KB, XOR-swizzled
  __shared__ float red[4][2][256];                        // 8 KB cross-wave reduce
  __shared__ float bS[VO], bQ[VO];                        // block-local BN stats

  for (int i=tid;i<VO;i+=256){ bS[i]=0.f; bQ[i]=0.f; }

  f32x4 acc0 = (f32x4){0.f,0.f,0.f,0.f};
  f32x4 acc1 = (f32x4){0.f,0.f,0.f,0.f};

  const float* frow = feat + (size_t)(rowBase + sr)*(J*DIN);
  float4 ld[16];

  auto issue = [&](int c){
    const float* src = frow + c*KC + sc*4;
    #pragma unroll
    for (int i=0;i<16;++i) ld[i] = *(const float4*)(src + i*64);
  };
  auto writeLDS = [&](int buf){
    #pragma unroll
    for (int i=0;i<16;++i){
      ushort4 hv;
      hv.x=f2bf(ld[i].x); hv.y=f2bf(ld[i].y); hv.z=f2bf(ld[i].z); hv.w=f2bf(ld[i].w);
      const int f = sc*4 + i*64;
      *(ushort4*)&Ab[buf][(sr*KC + f) ^ ((sr&7)<<3)] = hv;
    }
  };

  issue(0); writeLDS(0);
  __syncthreads();

  const int swz = (lo&7)<<3;

  for (int c=0;c<NCH;++c){
    const int buf = c&1;
    if (c+1<NCH) issue(c+1);
    const int v = c>>1;
    const unsigned short* Wv = Wbt + ((size_t)v*32 << 11);
    #pragma unroll
    for (int ks=0;ks<8;++ks){
      const int kl = w*256 + ks*32 + oc*8;       // k within chunk
      bf16x8 a = *(const bf16x8*)&Ab[buf][(lo*KC + kl) ^ swz];
      const int kg = (c&1)*KC + kl;              // k within v
      bf16x8 bA = *(const bf16x8*)(Wv + ((size_t)lo<<11) + kg);
      bf16x8 bB = *(const bf16x8*)(Wv + ((size_t)(16+lo)<<11) + kg);
      acc0 = __builtin_amdgcn_mfma_f32_16x16x32_bf16(a, bA, acc0, 0,0,0);
      acc1 = __builtin_amdgcn_mfma_f32_16x16x32_bf16(a, bB, acc1, 0,0,0);
    }
    if (c&1){
      #pragma unroll
      for (int r=0;r<4;++r){
        red[w][0][(oc*4+r)*16+lo] = acc0[r];
        red[w][1][(oc*4+r)*16+lo] = acc1[r];
      }
      acc0 = (f32x4){0.f,0.f,0.f,0.f};
      acc1 = (f32x4){0.f,0.f,0.f,0.f};
      __syncthreads();
      const int ri = sr*16+sc;
      float h0 = red[0][0][ri]+red[1][0][ri]+red[2][0][ri]+red[3][0][ri] + b0[v*J+sc];
      C[(size_t)(rowBase+sr)*VO + v*J + sc] = h0;
      float s0 = h0, q0 = h0*h0;
      float s1 = 0.f, q1 = 0.f;
      if (sc==0){
        const int r2 = sr*16;
        float h1 = red[0][1][r2]+red[1][1][r2]+red[2][1][r2]+red[3][1][r2] + b0[v*J+16];
        C[(size_t)(rowBase+sr)*VO + v*J + 16] = h1;
        s1 = h1; q1 = h1*h1;
      }
      s0 += __shfl_xor(s0,16); s0 += __shfl_xor(s0,32);
      q0 += __shfl_xor(q0,16); q0 += __shfl_xor(q0,32);
      s1 += __shfl_xor(s1,16); s1 += __shfl_xor(s1,32);
      q1 += __shfl_xor(q1,16); q1 += __shfl_xor(q1,32);
      if (l < 16){ atomicAdd(&bS[v*J+l], s0); atomicAdd(&bQ[v*J+l], q0); }
      if (l == 0){ atomicAdd(&bS[v*J+16], s1); atomicAdd(&bQ[v*J+16], q1); }
    }
    if (c+1<NCH){
      writeLDS(buf^1);
      __syncthreads();
    }
  }

  __syncthreads();
  const int rep = blockIdx.x & 7;
  for (int i=tid;i<VO;i+=256){
    atomicAdd(&stat0[rep*512+i],        bS[i]);
    atomicAdd(&stat0[4096 + rep*512+i], bQ[i]);
  }
}

// -------- PROBE: identical to conv0 but B-fragments are register constants (no Wbt reads).
// Writes to scratch C2/ST2 only. Measures the A-side (feat streaming) cost in isolation.
__global__ __launch_bounds__(256) void conv0_probe(
    const float* __restrict__ feat,
    const float* __restrict__ b0, float* __restrict__ C,
    float* __restrict__ stat0)
{
  const int tid = threadIdx.x, w = tid>>6, l = tid&63;
  const int lo = l&15, oc = l>>4;
  const int sr = tid>>4, sc = tid&15;
  const int rowBase = blockIdx.x*RT;

  __shared__ __align__(16) unsigned short Ab[2][RT*KC];
  __shared__ float red[4][2][256];
  __shared__ float bS[VO], bQ[VO];

  for (int i=tid;i<VO;i+=256){ bS[i]=0.f; bQ[i]=0.f; }

  f32x4 acc0 = (f32x4){0.f,0.f,0.f,0.f};
  f32x4 acc1 = (f32x4){0.f,0.f,0.f,0.f};

  const float* frow = feat + (size_t)(rowBase + sr)*(J*DIN);
  float4 ld[16];

  auto issue = [&](int c){
    const float* src = frow + c*KC + sc*4;
    #pragma unroll
    for (int i=0;i<16;++i) ld[i] = *(const float4*)(src + i*64);
  };
  auto writeLDS = [&](int buf){
    #pragma unroll
    for (int i=0;i<16;++i){
      ushort4 hv;
      hv.x=f2bf(ld[i].x); hv.y=f2bf(ld[i].y); hv.z=f2bf(ld[i].z); hv.w=f2bf(ld[i].w);
      const int f = sc*4 + i*64;
      *(ushort4*)&Ab[buf][(sr*KC + f) ^ ((sr&7)<<3)] = hv;
    }
  };

  issue(0); writeLDS(0);
  __syncthreads();

  const int swz = (lo&7)<<3;
  const bf16x8 kB = {0x3F80,0x3F80,0x3F80,0x3F80,0x3F80,0x3F80,0x3F80,0x3F80}; // bf16 1.0

  for (int c=0;c<NCH;++c){
    const int buf = c&1;
    if (c+1<NCH) issue(c+1);
    const int v = c>>1;
    #pragma unroll
    for (int ks=0;ks<8;++ks){
      const int kl = w*256 + ks*32 + oc*8;
      bf16x8 a = *(const bf16x8*)&Ab[buf][(lo*KC + kl) ^ swz];
      acc0 = __builtin_amdgcn_mfma_f32_16x16x32_bf16(a, kB, acc0, 0,0,0);
      acc1 = __builtin_amdgcn_mfma_f32_16x16x32_bf16(a, kB, acc1, 0,0,0);
    }
    if (c&1){
      #pragma unroll
      for (int r=0;r<4;++r){
        red[w][0][(oc*4+r)*16+lo] = acc0[r];
        red[w][1][(oc*4+r)*16+lo] = acc1[r];
      }
      acc0 = (f32x4){0.f,0.f,0.f,0.f};
      acc1 = (f32x4){0.f,0.f,0.f,0.f};
      __syncthreads();
      const int ri = sr*16+sc;
      float h0 = red[0][0][ri]+red[1][0][ri]+red[2][0][ri]+red[3][0][ri] + b0[v*J+sc];
      C[(size_t)(rowBase+sr)*VO + v*J + sc] = h0;
      float s0 = h0, q0 = h0*h0;
      float s1 = 0.f, q1 = 0.f;
      if (sc==0){
        const int r2 = sr*16;
        float h1 = red[0][1][r2]+red[1][1][r2]+red[2][1][r2]+red[3][1][r2] + b0[v*J+16];
        C[(size_t)(rowBase+sr)*VO + v*J + 16] = h1;
        s1 = h1; q1 = h1*h1;
      }
      s0 += __shfl_xor(s0,16); s0 += __shfl_xor(s0,32);
      q0 += __shfl_xor(q0,16); q0 += __shfl_xor(q0,32);
      s1 += __shfl_xor(s1,16); s1 += __shfl_xor(s1,32);
      q1 += __shfl_xor(q1,16); q1 += __shfl_xor(q1,32);
      if (l < 16){ atomicAdd(&bS[v*J+l], s0); atomicAdd(&bQ[v*J+l], q0); }
      if (l == 0){ atomicAdd(&bS[v*J+16], s1); atomicAdd(&bQ[v*J+16], q1); }
    }
    if (c+1<NCH){
      writeLDS(buf^1);
      __syncthreads();
    }
  }

  __syncthreads();
  const int rep = blockIdx.x & 7;
  for (int i=tid;i<VO;i+=256){
    atomicAdd(&stat0[rep*512+i],        bS[i]);
    atomicAdd(&stat0[4096 + rep*512+i], bQ[i]);
  }
}

// -------- chain (round-4 verbatim)
template<int RESID,int WRITEF,int CONV>
__global__ __launch_bounds__(256) void chain_kernel(
  const float* __restrict__ Cin, float* __restrict__ Cout,
  float* __restrict__ F,
  const float* __restrict__ statJ,
  const float* __restrict__ g, const float* __restrict__ be,
  const float* __restrict__ Wc, const float* __restrict__ bc,
  float* __restrict__ statN)
{
  __shared__ float wsmT[J*J*JP];      // [v][o][d], d-contiguous
  __shared__ float bb[VO];
  __shared__ float aC[VO], cC[VO];
  __shared__ float hbX[4][2][J*JP];   // per-wave, 2 rows, [vertex][chan] padded
  __shared__ float ssum[VO], ssq[VO];
  const int tid = threadIdx.x, wv = tid>>6, lane = tid&63;

  if (CONV) {
    for (int i=tid;i<J*J*J;i+=256) {
      int v = i/VO, rem = i - v*VO, d = rem/J, o = rem - d*J;
      wsmT[(v*J+o)*JP + d] = Wc[i];
    }
    for (int i=tid;i<VO;i+=256) bb[i]=bc[i];
  }
  for (int i=tid;i<VO;i+=256) {
    float s=0.f,q=0.f;
    #pragma unroll
    for (int r=0;r<8;++r){ s += statJ[r*512+i]; q += statJ[4096 + r*512+i]; }
    float mu  = s*(1.f/NB);
    float var = q*(1.f/NB) - mu*mu;
    float rs  = rsqrtf(var + EPSB);
    float A = rs*g[i];
    aC[i]=A; cC[i]=be[i]-mu*A;
    ssum[i]=0.f; ssq[i]=0.f;
  }
  __syncthreads();

  float sl[5]={0,0,0,0,0}, ql[5]={0,0,0,0,0};

  #pragma unroll
  for (int it=0; it<2; ++it) {
    const int r0 = blockIdx.x*16 + wv*4 + it*2;   // rows r0, r0+1
    const float* c0 = Cin + (size_t)r0*VO;
    const float* c1 = c0 + VO;

    #pragma unroll
    for (int s=0;s<5;++s) {
      int vo = lane + 64*s;
      if (vo<VO) {
        int vtx = vo/J, o = vo - vtx*J;
        hbX[wv][0][vtx*JP+o] = c0[vo]*aC[vo] + cC[vo];
        hbX[wv][1][vtx*JP+o] = c1[vo]*aC[vo] + cC[vo];
      }
    }
    asm volatile("s_waitcnt lgkmcnt(0)" ::: "memory");

    float n0[5], n1[5];
    #pragma unroll
    for (int s=0;s<5;++s) {
      int vo = lane + 64*s;
      n0[s]=0.f; n1[s]=0.f;
      if (vo<VO) {
        int vtx = vo/J, o = vo - vtx*J;
        unsigned m = ADJM[vtx];
        float a0=0.f, a1=0.f;
        while (m) {
          int u = __ffs(m) - 1; m &= m-1;
          a0 += hbX[wv][0][u*JP+o];
          a1 += hbX[wv][1][u*JP+o];
        }
        a0 = a0>0.f?a0:0.f; a1 = a1>0.f?a1:0.f;
        size_t gi = (size_t)r0*VO + vo;
        if (RESID)  { a0 += F[gi]; a1 += F[gi+VO]; }
        if (WRITEF) { F[gi]=a0;    F[gi+VO]=a1; }
        n0[s]=a0; n1[s]=a1;
        if (!CONV) { Cout[gi]=a0; Cout[gi+VO]=a1; }
      }
    }

    if (CONV) {
      #pragma unroll
      for (int s=0;s<5;++s) {
        int vo = lane + 64*s;
        if (vo<VO) {
          int vtx = vo/J, o = vo - vtx*J;
          hbX[wv][0][vtx*JP+o] = n0[s];
          hbX[wv][1][vtx*JP+o] = n1[s];
        }
      }
      asm volatile("s_waitcnt lgkmcnt(0)" ::: "memory");
      #pragma unroll
      for (int s=0;s<5;++s) {
        int vo = lane + 64*s;
        if (vo<VO) {
          int vtx = vo/J, o = vo - vtx*J;
          const float* wp = &wsmT[(vtx*J+o)*JP];
          const float* h0 = &hbX[wv][0][vtx*JP];
          const float* h1 = &hbX[wv][1][vtx*JP];
          float a0 = bb[vo], a1 = a0;
          #pragma unroll
          for (int d=0;d<J;++d) {
            float w = wp[d];
            a0 += h0[d]*w; a1 += h1[d]*w;
          }
          size_t gi = (size_t)r0*VO + vo;
          Cout[gi]=a0; Cout[gi+VO]=a1;
          sl[s] += a0+a1; ql[s] += a0*a0 + a1*a1;
        }
      }
      asm volatile("s_waitcnt lgkmcnt(0)" ::: "memory");
    } else {
      asm volatile("s_waitcnt lgkmcnt(0)" ::: "memory");
    }
  }

  if (CONV) {
    #pragma unroll
    for (int s=0;s<5;++s) {
      int vo = lane + 64*s;
      if (vo<VO) { atomicAdd(&ssum[vo], sl[s]); atomicAdd(&ssq[vo], ql[s]); }
    }
    __syncthreads();
    const int rep = blockIdx.x & 7;
    for (int i=tid;i<VO;i+=256) {
      atomicAdd(&statN[rep*512+i],        ssum[i]);
      atomicAdd(&statN[4096 + rep*512+i], ssq[i]);
    }
  }
}

extern "C" void kernel_launch(void* const* d_in, const int* in_sizes, int n_in,
                              void* d_out, int out_size, void* d_ws, size_t ws_size,
                              hipStream_t stream)
{
  (void)in_sizes; (void)n_in; (void)out_size; (void)ws_size;
  const float* img = (const float*)d_in[0];
  const float* W0  = (const float*)d_in[1];
  const float* b0  = (const float*)d_in[2];
  const float* g0  = (const float*)d_in[3];
  const float* be0 = (const float*)d_in[4];
  const float* Wr  = (const float*)d_in[5];
  const float* br  = (const float*)d_in[6];
  const float* gr  = (const float*)d_in[7];
  const float* ber = (const float*)d_in[8];

  float* ws = (float*)d_ws;
  // stats: 9 stages x 8192 floats (8 replicas x 512 sum, then 8 x 512 sumsq)
  float* ST = ws;                              // 73728 floats
  unsigned short* Wbt = (unsigned short*)(ws + 73728);   // 1114112 ushorts = 557056 floats
  float* Ca = ws + 73728 + 557056;
  float* Cb = Ca + (size_t)NB*VO;
  float* F  = Cb + (size_t)NB*VO;
  float* C2 = F  + (size_t)NB*VO;              // probe scratch C
  float* ST2 = C2 + (size_t)NB*VO;             // probe scratch stats (8192 floats)
  float* out = (float*)d_out;

  zero_stats<<<72,256,0,stream>>>(ST, 9*8192);
  zero_stats<<<8,256,0,stream>>>(ST2, 8192);
  wconv_kernel<<<136,256,0,stream>>>(W0, Wbt);

  conv0_kernel<<<512,256,0,stream>>>(img, Wbt, b0, Ca, ST);

  // ---- attribution probe: A-side only (no B reads), scratch outputs ----
  conv0_probe<<<512,256,0,stream>>>(img, b0, C2, ST2);

  const int W1 = J*J*J;
  #define STG(j) (ST + (j)*8192)
  chain_kernel<0,1,1><<<512,256,0,stream>>>(Ca, Cb, F, STG(0), g0,      be0,
                                            Wr+0*W1, br+0*VO, STG(1));
  chain_kernel<0,0,1><<<512,256,0,stream>>>(Cb, Ca, F, STG(1), gr+0*VO, ber+0*VO,
                                            Wr+1*W1, br+1*VO, STG(2));
  chain_kernel<1,1,1><<<512,256,0,stream>>>(Ca, Cb, F, STG(2), gr+1*VO, ber+1*VO,
                                            Wr+2*W1, br+2*VO, STG(3));
  chain_kernel<0,0,1><<<512,256,0,stream>>>(Cb, Ca, F, STG(3), gr+2*VO, ber+2*VO,
                                            Wr+3*W1, br+3*VO, STG(4));
  chain_kernel<1,1,1><<<512,256,0,stream>>>(Ca, Cb, F, STG(4), gr+3*VO, ber+3*VO,
                                            Wr+4*W1, br+4*VO, STG(5));
  chain_kernel<0,0,1><<<512,256,0,stream>>>(Cb, Ca, F, STG(5), gr+4*VO, ber+4*VO,
                                            Wr+5*W1, br+5*VO, STG(6));
  chain_kernel<1,1,1><<<512,256,0,stream>>>(Ca, Cb, F, STG(6), gr+5*VO, ber+5*VO,
                                            Wr+6*W1, br+6*VO, STG(7));
  chain_kernel<0,0,1><<<512,256,0,stream>>>(Cb, Ca, F, STG(7), gr+6*VO, ber+6*VO,
                                            Wr+7*W1, br+7*VO, STG(8));
  chain_kernel<1,0,0><<<512,256,0,stream>>>(Ca, out, F, STG(8), gr+7*VO, ber+7*VO,
                                            nullptr, nullptr, nullptr);
  #undef STG
}

// Round 11
// 472.929 us; speedup vs baseline: 1.5419x; 1.5419x over previous
//
#include <hip/hip_runtime.h>

#define J 17
#define JP 18             // padded inner dim (2-way LDS bank alias = free)
#define VO 289            // 17*17
#define NB 8192
#define DIN 2048
#define EPSB 1e-5f
#define KC 1024           // conv0: k-floats per staged chunk (4KB per row)
#define RT 16             // conv0: rows per block
#define NCH 34            // 17*2048/1024 chunks per row

typedef __attribute__((ext_vector_type(8))) short bf16x8;
typedef __attribute__((ext_vector_type(4))) float f32x4;
typedef __attribute__((ext_vector_type(4))) float f32x4v;   // native vector for nt loads

// adjacency (incl. self) as bitmasks, from SKEL
__device__ __constant__ unsigned ADJM[J] = {
  0x7u, 0xFu, 0x17u, 0x2Au, 0x54u, 0x8E8u, 0x1170u, 0x2A0u, 0x540u,
  0x280u, 0x500u, 0x3820u, 0x5840u, 0xA800u, 0x15000u, 0xA000u, 0x14000u};

__device__ inline unsigned short f2bf(float x){
  unsigned u = __float_as_uint(x);
  return (unsigned short)((u + 0x7fffu + ((u>>16)&1u)) >> 16);   // RNE
}

__global__ void zero_stats(float* p, int n) {
  int i = blockIdx.x*blockDim.x + threadIdx.x;
  int stride = gridDim.x*blockDim.x;
  for (; i < n; i += stride) p[i] = 0.f;
}

// -------- prepass: W0 [17][2048][17] f32 -> Wbt [17][32 cols][2048 k] bf16 (cols 17..31 zero)
__global__ __launch_bounds__(256) void wconv_kernel(
    const float* __restrict__ W0, unsigned short* __restrict__ Wbt)
{
  int t = blockIdx.x*256 + threadIdx.x;    // t = v*2048 + k
  int v = t >> 11, k = t & 2047;
  const float* src = W0 + (size_t)t*J;
  unsigned short* dst = Wbt + ((size_t)v*32 << 11) + k;
  #pragma unroll
  for (int o=0;o<J;++o)  dst[(size_t)o<<11] = f2bf(src[o]);
  #pragma unroll
  for (int o=J;o<32;++o) dst[(size_t)o<<11] = 0;
}

// -------- conv0 v4: streaming per-row GEMM, 4KB runs, NON-TEMPORAL A loads.
// 512 blocks x 16 rows, block 256 (4 waves). chunk c covers floats [c*1024,+1024); v = c>>1.
// nt A-loads keep the 1.14GB feat stream from evicting the 2.23MB Wbt out of L2.
__global__ __launch_bounds__(256) void conv0_kernel(
    const float* __restrict__ feat, const unsigned short* __restrict__ Wbt,
    const float* __restrict__ b0, float* __restrict__ C,
    float* __restrict__ stat0)
{
  const int tid = threadIdx.x, w = tid>>6, l = tid&63;
  const int lo = l&15, oc = l>>4;
  const int sr = tid>>4, sc = tid&15;       // staging: row, col-group
  const int rowBase = blockIdx.x*RT;

  __shared__ __align__(16) unsigned short Ab[2][RT*KC];   // 64 KB, XOR-swizzled
  __shared__ float red[4][2][256];                        // 8 KB cross-wave reduce
  __shared__ float bS[VO], bQ[VO];                        // block-local BN stats

  for (int i=tid;i<VO;i+=256){ bS[i]=0.f; bQ[i]=0.f; }

  f32x4 acc0 = (f32x4){0.f,0.f,0.f,0.f};
  f32x4 acc1 = (f32x4){0.f,0.f,0.f,0.f};

  const float* frow = feat + (size_t)(rowBase + sr)*(J*DIN);
  f32x4v ld[16];

  auto issue = [&](int c){
    const f32x4v* src = (const f32x4v*)(frow + c*KC + sc*4);
    #pragma unroll
    for (int i=0;i<16;++i) ld[i] = __builtin_nontemporal_load(src + i*16);
  };
  auto writeLDS = [&](int buf){
    #pragma unroll
    for (int i=0;i<16;++i){
      ushort4 hv;
      hv.x=f2bf(ld[i].x); hv.y=f2bf(ld[i].y); hv.z=f2bf(ld[i].z); hv.w=f2bf(ld[i].w);
      const int f = sc*4 + i*64;
      *(ushort4*)&Ab[buf][(sr*KC + f) ^ ((sr&7)<<3)] = hv;
    }
  };

  issue(0); writeLDS(0);
  __syncthreads();

  const int swz = (lo&7)<<3;

  for (int c=0;c<NCH;++c){
    const int buf = c&1;
    if (c+1<NCH) issue(c+1);
    const int v = c>>1;
    const unsigned short* Wv = Wbt + ((size_t)v*32 << 11);
    #pragma unroll
    for (int ks=0;ks<8;++ks){
      const int kl = w*256 + ks*32 + oc*8;       // k within chunk
      bf16x8 a = *(const bf16x8*)&Ab[buf][(lo*KC + kl) ^ swz];
      const int kg = (c&1)*KC + kl;              // k within v
      bf16x8 bA = *(const bf16x8*)(Wv + ((size_t)lo<<11) + kg);
      bf16x8 bB = *(const bf16x8*)(Wv + ((size_t)(16+lo)<<11) + kg);
      acc0 = __builtin_amdgcn_mfma_f32_16x16x32_bf16(a, bA, acc0, 0,0,0);
      acc1 = __builtin_amdgcn_mfma_f32_16x16x32_bf16(a, bB, acc1, 0,0,0);
    }
    if (c&1){
      // v complete: cross-wave k-split reduce + epilogue
      #pragma unroll
      for (int r=0;r<4;++r){
        red[w][0][(oc*4+r)*16+lo] = acc0[r];
        red[w][1][(oc*4+r)*16+lo] = acc1[r];
      }
      acc0 = (f32x4){0.f,0.f,0.f,0.f};
      acc1 = (f32x4){0.f,0.f,0.f,0.f};
      __syncthreads();
      const int ri = sr*16+sc;
      float h0 = red[0][0][ri]+red[1][0][ri]+red[2][0][ri]+red[3][0][ri] + b0[v*J+sc];
      C[(size_t)(rowBase+sr)*VO + v*J + sc] = h0;
      float s0 = h0, q0 = h0*h0;
      float s1 = 0.f, q1 = 0.f;
      if (sc==0){
        const int r2 = sr*16;
        float h1 = red[0][1][r2]+red[1][1][r2]+red[2][1][r2]+red[3][1][r2] + b0[v*J+16];
        C[(size_t)(rowBase+sr)*VO + v*J + 16] = h1;
        s1 = h1; q1 = h1*h1;
      }
      s0 += __shfl_xor(s0,16); s0 += __shfl_xor(s0,32);
      q0 += __shfl_xor(q0,16); q0 += __shfl_xor(q0,32);
      s1 += __shfl_xor(s1,16); s1 += __shfl_xor(s1,32);
      q1 += __shfl_xor(q1,16); q1 += __shfl_xor(q1,32);
      if (l < 16){ atomicAdd(&bS[v*J+l], s0); atomicAdd(&bQ[v*J+l], q0); }
      if (l == 0){ atomicAdd(&bS[v*J+16], s1); atomicAdd(&bQ[v*J+16], q1); }
    }
    if (c+1<NCH){
      writeLDS(buf^1);
      __syncthreads();
    }
  }

  __syncthreads();
  const int rep = blockIdx.x & 7;
  for (int i=tid;i<VO;i+=256){
    atomicAdd(&stat0[rep*512+i],        bS[i]);
    atomicAdd(&stat0[4096 + rep*512+i], bQ[i]);
  }
}

// -------- chain: BN_j (8-replica stats) -> bitmask adjacency -> ReLU [-> resid/F]
//          [-> conv_{j+1} (transposed W, 2-row pairing) -> replica stats]   [round-4 verbatim]
template<int RESID,int WRITEF,int CONV>
__global__ __launch_bounds__(256) void chain_kernel(
  const float* __restrict__ Cin, float* __restrict__ Cout,
  float* __restrict__ F,
  const float* __restrict__ statJ,
  const float* __restrict__ g, const float* __restrict__ be,
  const float* __restrict__ Wc, const float* __restrict__ bc,
  float* __restrict__ statN)
{
  __shared__ float wsmT[J*J*JP];      // [v][o][d], d-contiguous
  __shared__ float bb[VO];
  __shared__ float aC[VO], cC[VO];
  __shared__ float hbX[4][2][J*JP];   // per-wave, 2 rows, [vertex][chan] padded
  __shared__ float ssum[VO], ssq[VO];
  const int tid = threadIdx.x, wv = tid>>6, lane = tid&63;

  if (CONV) {
    for (int i=tid;i<J*J*J;i+=256) {
      int v = i/VO, rem = i - v*VO, d = rem/J, o = rem - d*J;
      wsmT[(v*J+o)*JP + d] = Wc[i];
    }
    for (int i=tid;i<VO;i+=256) bb[i]=bc[i];
  }
  for (int i=tid;i<VO;i+=256) {
    float s=0.f,q=0.f;
    #pragma unroll
    for (int r=0;r<8;++r){ s += statJ[r*512+i]; q += statJ[4096 + r*512+i]; }
    float mu  = s*(1.f/NB);
    float var = q*(1.f/NB) - mu*mu;
    float rs  = rsqrtf(var + EPSB);
    float A = rs*g[i];
    aC[i]=A; cC[i]=be[i]-mu*A;
    ssum[i]=0.f; ssq[i]=0.f;
  }
  __syncthreads();

  float sl[5]={0,0,0,0,0}, ql[5]={0,0,0,0,0};

  #pragma unroll
  for (int it=0; it<2; ++it) {
    const int r0 = blockIdx.x*16 + wv*4 + it*2;   // rows r0, r0+1
    const float* c0 = Cin + (size_t)r0*VO;
    const float* c1 = c0 + VO;

    #pragma unroll
    for (int s=0;s<5;++s) {
      int vo = lane + 64*s;
      if (vo<VO) {
        int vtx = vo/J, o = vo - vtx*J;
        hbX[wv][0][vtx*JP+o] = c0[vo]*aC[vo] + cC[vo];
        hbX[wv][1][vtx*JP+o] = c1[vo]*aC[vo] + cC[vo];
      }
    }
    asm volatile("s_waitcnt lgkmcnt(0)" ::: "memory");

    float n0[5], n1[5];
    #pragma unroll
    for (int s=0;s<5;++s) {
      int vo = lane + 64*s;
      n0[s]=0.f; n1[s]=0.f;
      if (vo<VO) {
        int vtx = vo/J, o = vo - vtx*J;
        unsigned m = ADJM[vtx];
        float a0=0.f, a1=0.f;
        while (m) {
          int u = __ffs(m) - 1; m &= m-1;
          a0 += hbX[wv][0][u*JP+o];
          a1 += hbX[wv][1][u*JP+o];
        }
        a0 = a0>0.f?a0:0.f; a1 = a1>0.f?a1:0.f;
        size_t gi = (size_t)r0*VO + vo;
        if (RESID)  { a0 += F[gi]; a1 += F[gi+VO]; }
        if (WRITEF) { F[gi]=a0;    F[gi+VO]=a1; }
        n0[s]=a0; n1[s]=a1;
        if (!CONV) { Cout[gi]=a0; Cout[gi+VO]=a1; }
      }
    }

    if (CONV) {
      #pragma unroll
      for (int s=0;s<5;++s) {
        int vo = lane + 64*s;
        if (vo<VO) {
          int vtx = vo/J, o = vo - vtx*J;
          hbX[wv][0][vtx*JP+o] = n0[s];
          hbX[wv][1][vtx*JP+o] = n1[s];
        }
      }
      asm volatile("s_waitcnt lgkmcnt(0)" ::: "memory");
      #pragma unroll
      for (int s=0;s<5;++s) {
        int vo = lane + 64*s;
        if (vo<VO) {
          int vtx = vo/J, o = vo - vtx*J;
          const float* wp = &wsmT[(vtx*J+o)*JP];
          const float* h0 = &hbX[wv][0][vtx*JP];
          const float* h1 = &hbX[wv][1][vtx*JP];
          float a0 = bb[vo], a1 = a0;
          #pragma unroll
          for (int d=0;d<J;++d) {
            float w = wp[d];
            a0 += h0[d]*w; a1 += h1[d]*w;
          }
          size_t gi = (size_t)r0*VO + vo;
          Cout[gi]=a0; Cout[gi+VO]=a1;
          sl[s] += a0+a1; ql[s] += a0*a0 + a1*a1;
        }
      }
      asm volatile("s_waitcnt lgkmcnt(0)" ::: "memory");
    } else {
      asm volatile("s_waitcnt lgkmcnt(0)" ::: "memory");
    }
  }

  if (CONV) {
    #pragma unroll
    for (int s=0;s<5;++s) {
      int vo = lane + 64*s;
      if (vo<VO) { atomicAdd(&ssum[vo], sl[s]); atomicAdd(&ssq[vo], ql[s]); }
    }
    __syncthreads();
    const int rep = blockIdx.x & 7;
    for (int i=tid;i<VO;i+=256) {
      atomicAdd(&statN[rep*512+i],        ssum[i]);
      atomicAdd(&statN[4096 + rep*512+i], ssq[i]);
    }
  }
}

extern "C" void kernel_launch(void* const* d_in, const int* in_sizes, int n_in,
                              void* d_out, int out_size, void* d_ws, size_t ws_size,
                              hipStream_t stream)
{
  (void)in_sizes; (void)n_in; (void)out_size; (void)ws_size;
  const float* img = (const float*)d_in[0];
  const float* W0  = (const float*)d_in[1];
  const float* b0  = (const float*)d_in[2];
  const float* g0  = (const float*)d_in[3];
  const float* be0 = (const float*)d_in[4];
  const float* Wr  = (const float*)d_in[5];
  const float* br  = (const float*)d_in[6];
  const float* gr  = (const float*)d_in[7];
  const float* ber = (const float*)d_in[8];

  float* ws = (float*)d_ws;
  // stats: 9 stages x 8192 floats (8 replicas x 512 sum, then 8 x 512 sumsq)
  float* ST = ws;                              // 73728 floats
  unsigned short* Wbt = (unsigned short*)(ws + 73728);   // 1114112 ushorts = 557056 floats
  float* Ca = ws + 73728 + 557056;
  float* Cb = Ca + (size_t)NB*VO;
  float* F  = Cb + (size_t)NB*VO;
  float* out = (float*)d_out;

  zero_stats<<<72,256,0,stream>>>(ST, 9*8192);
  wconv_kernel<<<136,256,0,stream>>>(W0, Wbt);

  conv0_kernel<<<512,256,0,stream>>>(img, Wbt, b0, Ca, ST);

  const int W1 = J*J*J;
  #define STG(j) (ST + (j)*8192)
  chain_kernel<0,1,1><<<512,256,0,stream>>>(Ca, Cb, F, STG(0), g0,      be0,
                                            Wr+0*W1, br+0*VO, STG(1));
  chain_kernel<0,0,1><<<512,256,0,stream>>>(Cb, Ca, F, STG(1), gr+0*VO, ber+0*VO,
                                            Wr+1*W1, br+1*VO, STG(2));
  chain_kernel<1,1,1><<<512,256,0,stream>>>(Ca, Cb, F, STG(2), gr+1*VO, ber+1*VO,
                                            Wr+2*W1, br+2*VO, STG(3));
  chain_kernel<0,0,1><<<512,256,0,stream>>>(Cb, Ca, F, STG(3), gr+2*VO, ber+2*VO,
                                            Wr+3*W1, br+3*VO, STG(4));
  chain_kernel<1,1,1><<<512,256,0,stream>>>(Ca, Cb, F, STG(4), gr+3*VO, ber+3*VO,
                                            Wr+4*W1, br+4*VO, STG(5));
  chain_kernel<0,0,1><<<512,256,0,stream>>>(Cb, Ca, F, STG(5), gr+4*VO, ber+4*VO,
                                            Wr+5*W1, br+5*VO, STG(6));
  chain_kernel<1,1,1><<<512,256,0,stream>>>(Ca, Cb, F, STG(6), gr+5*VO, ber+5*VO,
                                            Wr+6*W1, br+6*VO, STG(7));
  chain_kernel<0,0,1><<<512,256,0,stream>>>(Cb, Ca, F, STG(7), gr+6*VO, ber+6*VO,
                                            Wr+7*W1, br+7*VO, STG(8));
  chain_kernel<1,0,0><<<512,256,0,stream>>>(Ca, out, F, STG(8), gr+7*VO, ber+7*VO,
                                            nullptr, nullptr, nullptr);
  #undef STG
}

// Round 12
// 441.569 us; speedup vs baseline: 1.6514x; 1.0710x over previous
//
#include <hip/hip_runtime.h>

#define J 17
#define JP 18             // padded inner dim (2-way LDS bank alias = free)
#define VO 289            // 17*17
#define NB 8192
#define DIN 2048
#define EPSB 1e-5f
#define KC 512            // conv0: k-floats per staged chunk (2KB per row)
#define RT 32             // conv0: rows per block
#define NCH 68            // 17*2048/512 chunks per row

typedef __attribute__((ext_vector_type(8))) short bf16x8;
typedef __attribute__((ext_vector_type(4))) float f32x4;
typedef __attribute__((ext_vector_type(4))) float f32x4v;   // native vector for nt loads

// adjacency (incl. self) as bitmasks, from SKEL
__device__ __constant__ unsigned ADJM[J] = {
  0x7u, 0xFu, 0x17u, 0x2Au, 0x54u, 0x8E8u, 0x1170u, 0x2A0u, 0x540u,
  0x280u, 0x500u, 0x3820u, 0x5840u, 0xA800u, 0x15000u, 0xA000u, 0x14000u};

__device__ inline unsigned short f2bf(float x){
  unsigned u = __float_as_uint(x);
  return (unsigned short)((u + 0x7fffu + ((u>>16)&1u)) >> 16);   // RNE
}

__global__ void zero_stats(float* p, int n) {
  int i = blockIdx.x*blockDim.x + threadIdx.x;
  int stride = gridDim.x*blockDim.x;
  for (; i < n; i += stride) p[i] = 0.f;
}

// -------- prepass: W0 [17][2048][17] f32 -> Wbt [17][32 cols][2048 k] bf16 (cols 17..31 zero)
__global__ __launch_bounds__(256) void wconv_kernel(
    const float* __restrict__ W0, unsigned short* __restrict__ Wbt)
{
  int t = blockIdx.x*256 + threadIdx.x;    // t = v*2048 + k
  int v = t >> 11, k = t & 2047;
  const float* src = W0 + (size_t)t*J;
  unsigned short* dst = Wbt + ((size_t)v*32 << 11) + k;
  #pragma unroll
  for (int o=0;o<J;++o)  dst[(size_t)o<<11] = f2bf(src[o]);
  #pragma unroll
  for (int o=J;o<32;++o) dst[(size_t)o<<11] = 0;
}

// -------- conv0 v5: streaming per-row GEMM. 256 blocks x 32 rows, block 512 (8 waves).
// chunk c covers floats [c*512,+512) of each row; v = c>>2. nt A loads; B fragments:
// bA = cols 0-15, bB sparse (only lane lo==0 loads col 16; cols 17-31 are zero -> never fetched).
// Each B fragment feeds 2 row-tiles (a0: rows 0-15, a1: rows 16-31) -> B amortized over 32 rows.
__global__ __launch_bounds__(512) void conv0_kernel(
    const float* __restrict__ feat, const unsigned short* __restrict__ Wbt,
    const float* __restrict__ b0, float* __restrict__ C,
    float* __restrict__ stat0)
{
  const int tid = threadIdx.x, w = tid>>6, l = tid&63;
  const int lo = l&15, oc = l>>4;
  const int sr = tid>>4, sc = tid&15;       // staging: 16 threads/row, 32 rows
  const int rowBase = blockIdx.x*RT;

  __shared__ __align__(16) unsigned short Ab[2][RT*KC];   // 64 KB, XOR-swizzled
  __shared__ float red[8][2][256];                        // 16 KB cross-wave reduce
  __shared__ float bS[VO], bQ[VO];                        // block-local BN stats

  for (int i=tid;i<VO;i+=512){ bS[i]=0.f; bQ[i]=0.f; }

  f32x4 acc00 = (f32x4){0.f,0.f,0.f,0.f};
  f32x4 acc01 = (f32x4){0.f,0.f,0.f,0.f};
  f32x4 acc10 = (f32x4){0.f,0.f,0.f,0.f};
  f32x4 acc11 = (f32x4){0.f,0.f,0.f,0.f};

  const float* frow = feat + (size_t)(rowBase + sr)*(J*DIN);
  f32x4v ld[8];

  auto issue = [&](int c){
    const f32x4v* src = (const f32x4v*)(frow + c*KC + sc*4);
    #pragma unroll
    for (int i=0;i<8;++i) ld[i] = __builtin_nontemporal_load(src + i*16);
  };
  auto writeLDS = [&](int buf){
    #pragma unroll
    for (int i=0;i<8;++i){
      ushort4 hv;
      hv.x=f2bf(ld[i].x); hv.y=f2bf(ld[i].y); hv.z=f2bf(ld[i].z); hv.w=f2bf(ld[i].w);
      const int f = sc*4 + i*64;
      *(ushort4*)&Ab[buf][(sr*KC + f) ^ ((sr&7)<<3)] = hv;
    }
  };

  issue(0); writeLDS(0);
  __syncthreads();

  const int swz = (lo&7)<<3;   // same for row lo and row 16+lo

  for (int c=0;c<NCH;++c){
    const int buf = c&1;
    if (c+1<NCH) issue(c+1);
    const int v = c>>2;
    const unsigned short* Wv = Wbt + ((size_t)v*32 << 11);
    #pragma unroll
    for (int ks=0;ks<2;++ks){
      const int kl = w*64 + ks*32 + oc*8;        // k within chunk (8 waves x 64)
      bf16x8 a0 = *(const bf16x8*)&Ab[buf][(lo*KC + kl) ^ swz];
      bf16x8 a1 = *(const bf16x8*)&Ab[buf][((16+lo)*KC + kl) ^ swz];
      const int kg = (c&3)*KC + kl;              // k within v
      bf16x8 bA = *(const bf16x8*)(Wv + ((size_t)lo<<11) + kg);
      bf16x8 bB = {0,0,0,0,0,0,0,0};
      if (lo==0) bB = *(const bf16x8*)(Wv + ((size_t)16<<11) + kg);
      acc00 = __builtin_amdgcn_mfma_f32_16x16x32_bf16(a0, bA, acc00, 0,0,0);
      acc10 = __builtin_amdgcn_mfma_f32_16x16x32_bf16(a1, bA, acc10, 0,0,0);
      acc01 = __builtin_amdgcn_mfma_f32_16x16x32_bf16(a0, bB, acc01, 0,0,0);
      acc11 = __builtin_amdgcn_mfma_f32_16x16x32_bf16(a1, bB, acc11, 0,0,0);
    }
    if ((c&3)==3){
      // ---- v complete: two-pass cross-wave reduce + epilogue (rows 0-15, then 16-31)
      #pragma unroll
      for (int pass=0; pass<2; ++pass){
        #pragma unroll
        for (int r=0;r<4;++r){
          red[w][0][(oc*4+r)*16+lo] = pass ? acc10[r] : acc00[r];
          red[w][1][(oc*4+r)*16+lo] = pass ? acc11[r] : acc01[r];
        }
        __syncthreads();
        if (tid < 256){
          const int er = tid>>4, ec = tid&15;    // row within tile, col
          const int ri = er*16+ec;
          float h0 = red[0][0][ri]+red[1][0][ri]+red[2][0][ri]+red[3][0][ri]
                   + red[4][0][ri]+red[5][0][ri]+red[6][0][ri]+red[7][0][ri]
                   + b0[v*J+ec];
          const int row = rowBase + pass*16 + er;
          C[(size_t)row*VO + v*J + ec] = h0;
          float s0 = h0, q0 = h0*h0;
          float s1 = 0.f, q1 = 0.f;
          if (ec==0){
            const int r2 = er*16;
            float h1 = red[0][1][r2]+red[1][1][r2]+red[2][1][r2]+red[3][1][r2]
                     + red[4][1][r2]+red[5][1][r2]+red[6][1][r2]+red[7][1][r2]
                     + b0[v*J+16];
            C[(size_t)row*VO + v*J + 16] = h1;
            s1 = h1; q1 = h1*h1;
          }
          s0 += __shfl_xor(s0,16); s0 += __shfl_xor(s0,32);
          q0 += __shfl_xor(q0,16); q0 += __shfl_xor(q0,32);
          s1 += __shfl_xor(s1,16); s1 += __shfl_xor(s1,32);
          q1 += __shfl_xor(q1,16); q1 += __shfl_xor(q1,32);
          if (l < 16){ atomicAdd(&bS[v*J+l], s0); atomicAdd(&bQ[v*J+l], q0); }
          if (l == 0){ atomicAdd(&bS[v*J+16], s1); atomicAdd(&bQ[v*J+16], q1); }
        }
        __syncthreads();
      }
      acc00 = (f32x4){0.f,0.f,0.f,0.f};
      acc01 = (f32x4){0.f,0.f,0.f,0.f};
      acc10 = (f32x4){0.f,0.f,0.f,0.f};
      acc11 = (f32x4){0.f,0.f,0.f,0.f};
    }
    if (c+1<NCH){
      writeLDS(buf^1);
      __syncthreads();
    }
  }

  __syncthreads();
  const int rep = blockIdx.x & 7;
  for (int i=tid;i<VO;i+=512){
    atomicAdd(&stat0[rep*512+i],        bS[i]);
    atomicAdd(&stat0[4096 + rep*512+i], bQ[i]);
  }
}

// -------- chain: BN_j (8-replica stats) -> bitmask adjacency -> ReLU [-> resid/F]
//          [-> conv_{j+1} (transposed W, 2-row pairing) -> replica stats]   [round-4 verbatim]
template<int RESID,int WRITEF,int CONV>
__global__ __launch_bounds__(256) void chain_kernel(
  const float* __restrict__ Cin, float* __restrict__ Cout,
  float* __restrict__ F,
  const float* __restrict__ statJ,
  const float* __restrict__ g, const float* __restrict__ be,
  const float* __restrict__ Wc, const float* __restrict__ bc,
  float* __restrict__ statN)
{
  __shared__ float wsmT[J*J*JP];      // [v][o][d], d-contiguous
  __shared__ float bb[VO];
  __shared__ float aC[VO], cC[VO];
  __shared__ float hbX[4][2][J*JP];   // per-wave, 2 rows, [vertex][chan] padded
  __shared__ float ssum[VO], ssq[VO];
  const int tid = threadIdx.x, wv = tid>>6, lane = tid&63;

  if (CONV) {
    for (int i=tid;i<J*J*J;i+=256) {
      int v = i/VO, rem = i - v*VO, d = rem/J, o = rem - d*J;
      wsmT[(v*J+o)*JP + d] = Wc[i];
    }
    for (int i=tid;i<VO;i+=256) bb[i]=bc[i];
  }
  for (int i=tid;i<VO;i+=256) {
    float s=0.f,q=0.f;
    #pragma unroll
    for (int r=0;r<8;++r){ s += statJ[r*512+i]; q += statJ[4096 + r*512+i]; }
    float mu  = s*(1.f/NB);
    float var = q*(1.f/NB) - mu*mu;
    float rs  = rsqrtf(var + EPSB);
    float A = rs*g[i];
    aC[i]=A; cC[i]=be[i]-mu*A;
    ssum[i]=0.f; ssq[i]=0.f;
  }
  __syncthreads();

  float sl[5]={0,0,0,0,0}, ql[5]={0,0,0,0,0};

  #pragma unroll
  for (int it=0; it<2; ++it) {
    const int r0 = blockIdx.x*16 + wv*4 + it*2;   // rows r0, r0+1
    const float* c0 = Cin + (size_t)r0*VO;
    const float* c1 = c0 + VO;

    #pragma unroll
    for (int s=0;s<5;++s) {
      int vo = lane + 64*s;
      if (vo<VO) {
        int vtx = vo/J, o = vo - vtx*J;
        hbX[wv][0][vtx*JP+o] = c0[vo]*aC[vo] + cC[vo];
        hbX[wv][1][vtx*JP+o] = c1[vo]*aC[vo] + cC[vo];
      }
    }
    asm volatile("s_waitcnt lgkmcnt(0)" ::: "memory");

    float n0[5], n1[5];
    #pragma unroll
    for (int s=0;s<5;++s) {
      int vo = lane + 64*s;
      n0[s]=0.f; n1[s]=0.f;
      if (vo<VO) {
        int vtx = vo/J, o = vo - vtx*J;
        unsigned m = ADJM[vtx];
        float a0=0.f, a1=0.f;
        while (m) {
          int u = __ffs(m) - 1; m &= m-1;
          a0 += hbX[wv][0][u*JP+o];
          a1 += hbX[wv][1][u*JP+o];
        }
        a0 = a0>0.f?a0:0.f; a1 = a1>0.f?a1:0.f;
        size_t gi = (size_t)r0*VO + vo;
        if (RESID)  { a0 += F[gi]; a1 += F[gi+VO]; }
        if (WRITEF) { F[gi]=a0;    F[gi+VO]=a1; }
        n0[s]=a0; n1[s]=a1;
        if (!CONV) { Cout[gi]=a0; Cout[gi+VO]=a1; }
      }
    }

    if (CONV) {
      #pragma unroll
      for (int s=0;s<5;++s) {
        int vo = lane + 64*s;
        if (vo<VO) {
          int vtx = vo/J, o = vo - vtx*J;
          hbX[wv][0][vtx*JP+o] = n0[s];
          hbX[wv][1][vtx*JP+o] = n1[s];
        }
      }
      asm volatile("s_waitcnt lgkmcnt(0)" ::: "memory");
      #pragma unroll
      for (int s=0;s<5;++s) {
        int vo = lane + 64*s;
        if (vo<VO) {
          int vtx = vo/J, o = vo - vtx*J;
          const float* wp = &wsmT[(vtx*J+o)*JP];
          const float* h0 = &hbX[wv][0][vtx*JP];
          const float* h1 = &hbX[wv][1][vtx*JP];
          float a0 = bb[vo], a1 = a0;
          #pragma unroll
          for (int d=0;d<J;++d) {
            float w = wp[d];
            a0 += h0[d]*w; a1 += h1[d]*w;
          }
          size_t gi = (size_t)r0*VO + vo;
          Cout[gi]=a0; Cout[gi+VO]=a1;
          sl[s] += a0+a1; ql[s] += a0*a0 + a1*a1;
        }
      }
      asm volatile("s_waitcnt lgkmcnt(0)" ::: "memory");
    } else {
      asm volatile("s_waitcnt lgkmcnt(0)" ::: "memory");
    }
  }

  if (CONV) {
    #pragma unroll
    for (int s=0;s<5;++s) {
      int vo = lane + 64*s;
      if (vo<VO) { atomicAdd(&ssum[vo], sl[s]); atomicAdd(&ssq[vo], ql[s]); }
    }
    __syncthreads();
    const int rep = blockIdx.x & 7;
    for (int i=tid;i<VO;i+=256) {
      atomicAdd(&statN[rep*512+i],        ssum[i]);
      atomicAdd(&statN[4096 + rep*512+i], ssq[i]);
    }
  }
}

extern "C" void kernel_launch(void* const* d_in, const int* in_sizes, int n_in,
                              void* d_out, int out_size, void* d_ws, size_t ws_size,
                              hipStream_t stream)
{
  (void)in_sizes; (void)n_in; (void)out_size; (void)ws_size;
  const float* img = (const float*)d_in[0];
  const float* W0  = (const float*)d_in[1];
  const float* b0  = (const float*)d_in[2];
  const float* g0  = (const float*)d_in[3];
  const float* be0 = (const float*)d_in[4];
  const float* Wr  = (const float*)d_in[5];
  const float* br  = (const float*)d_in[6];
  const float* gr  = (const float*)d_in[7];
  const float* ber = (const float*)d_in[8];

  float* ws = (float*)d_ws;
  // stats: 9 stages x 8192 floats (8 replicas x 512 sum, then 8 x 512 sumsq)
  float* ST = ws;                              // 73728 floats
  unsigned short* Wbt = (unsigned short*)(ws + 73728);   // 1114112 ushorts = 557056 floats
  float* Ca = ws + 73728 + 557056;
  float* Cb = Ca + (size_t)NB*VO;
  float* F  = Cb + (size_t)NB*VO;
  float* out = (float*)d_out;

  zero_stats<<<72,256,0,stream>>>(ST, 9*8192);
  wconv_kernel<<<136,256,0,stream>>>(W0, Wbt);

  conv0_kernel<<<256,512,0,stream>>>(img, Wbt, b0, Ca, ST);

  const int W1 = J*J*J;
  #define STG(j) (ST + (j)*8192)
  chain_kernel<0,1,1><<<512,256,0,stream>>>(Ca, Cb, F, STG(0), g0,      be0,
                                            Wr+0*W1, br+0*VO, STG(1));
  chain_kernel<0,0,1><<<512,256,0,stream>>>(Cb, Ca, F, STG(1), gr+0*VO, ber+0*VO,
                                            Wr+1*W1, br+1*VO, STG(2));
  chain_kernel<1,1,1><<<512,256,0,stream>>>(Ca, Cb, F, STG(2), gr+1*VO, ber+1*VO,
                                            Wr+2*W1, br+2*VO, STG(3));
  chain_kernel<0,0,1><<<512,256,0,stream>>>(Cb, Ca, F, STG(3), gr+2*VO, ber+2*VO,
                                            Wr+3*W1, br+3*VO, STG(4));
  chain_kernel<1,1,1><<<512,256,0,stream>>>(Ca, Cb, F, STG(4), gr+3*VO, ber+3*VO,
                                            Wr+4*W1, br+4*VO, STG(5));
  chain_kernel<0,0,1><<<512,256,0,stream>>>(Cb, Ca, F, STG(5), gr+4*VO, ber+4*VO,
                                            Wr+5*W1, br+5*VO, STG(6));
  chain_kernel<1,1,1><<<512,256,0,stream>>>(Ca, Cb, F, STG(6), gr+5*VO, ber+5*VO,
                                            Wr+6*W1, br+6*VO, STG(7));
  chain_kernel<0,0,1><<<512,256,0,stream>>>(Cb, Ca, F, STG(7), gr+6*VO, ber+6*VO,
                                            Wr+7*W1, br+7*VO, STG(8));
  chain_kernel<1,0,0><<<512,256,0,stream>>>(Ca, out, F, STG(8), gr+7*VO, ber+7*VO,
                                            nullptr, nullptr, nullptr);
  #undef STG
}

// Round 13
// 431.303 us; speedup vs baseline: 1.6907x; 1.0238x over previous
//
#include <hip/hip_runtime.h>

#define J 17
#define JP 18             // padded inner dim (2-way LDS bank alias = free)
#define VO 289            // 17*17
#define NB 8192
#define DIN 2048
#define EPSB 1e-5f
#define KC 512            // conv0: k-floats per staged chunk (2KB per row)
#define RT 32             // conv0: rows per block
#define NCH 68            // 17*2048/512 chunks per row

typedef __attribute__((ext_vector_type(8))) short bf16x8;
typedef __attribute__((ext_vector_type(4))) float f32x4;
typedef __attribute__((ext_vector_type(4))) float f32x4v;   // native vector for nt loads

// adjacency (incl. self) as bitmasks, from SKEL
__device__ __constant__ unsigned ADJM[J] = {
  0x7u, 0xFu, 0x17u, 0x2Au, 0x54u, 0x8E8u, 0x1170u, 0x2A0u, 0x540u,
  0x280u, 0x500u, 0x3820u, 0x5840u, 0xA800u, 0x15000u, 0xA000u, 0x14000u};

__device__ inline unsigned short f2bf(float x){
  unsigned u = __float_as_uint(x);
  return (unsigned short)((u + 0x7fffu + ((u>>16)&1u)) >> 16);   // RNE
}

__global__ void zero_stats(float* p, int n) {
  int i = blockIdx.x*blockDim.x + threadIdx.x;
  int stride = gridDim.x*blockDim.x;
  for (; i < n; i += stride) p[i] = 0.f;
}

// -------- prepass: W0 [17][2048][17] f32 -> Wp fragment-major:
// Wp[v][kb=k/8][col 0..16][8 ushorts]  (17*256*17*8 ushorts ~ 1.18 MB)
// A wave's B-fragment read = 16 lanes x consecutive 16B = 256B contiguous.
__global__ __launch_bounds__(256) void wconv_kernel(
    const float* __restrict__ W0, unsigned short* __restrict__ Wp)
{
  int t = blockIdx.x*256 + threadIdx.x;    // t = v*2048 + k  (34816 threads)
  int v = t >> 11, k = t & 2047;
  const float* src = W0 + (size_t)t*J;
  unsigned short* dst = Wp + (((size_t)v*256 + (k>>3))*17)*8 + (k&7);
  #pragma unroll
  for (int o=0;o<J;++o)  dst[o*8] = f2bf(src[o]);
}

// -------- conv0 v6: streaming per-row GEMM. 256 blocks x 32 rows, block 512 (8 waves).
// chunk c covers floats [c*512,+512); v = c>>2. nt A loads; fragment-major B (coalesced).
// bB sparse: only lane lo==0 loads col 16. Each B fragment feeds 2 row-tiles.
__global__ __launch_bounds__(512) void conv0_kernel(
    const float* __restrict__ feat, const unsigned short* __restrict__ Wp,
    const float* __restrict__ b0, float* __restrict__ C,
    float* __restrict__ stat0)
{
  const int tid = threadIdx.x, w = tid>>6, l = tid&63;
  const int lo = l&15, oc = l>>4;
  const int sr = tid>>4, sc = tid&15;       // staging: 16 threads/row, 32 rows
  const int rowBase = blockIdx.x*RT;

  __shared__ __align__(16) unsigned short Ab[2][RT*KC];   // 64 KB, XOR-swizzled
  __shared__ float red[8][2][256];                        // 16 KB cross-wave reduce
  __shared__ float bS[VO], bQ[VO];                        // block-local BN stats

  for (int i=tid;i<VO;i+=512){ bS[i]=0.f; bQ[i]=0.f; }

  f32x4 acc00 = (f32x4){0.f,0.f,0.f,0.f};
  f32x4 acc01 = (f32x4){0.f,0.f,0.f,0.f};
  f32x4 acc10 = (f32x4){0.f,0.f,0.f,0.f};
  f32x4 acc11 = (f32x4){0.f,0.f,0.f,0.f};

  const float* frow = feat + (size_t)(rowBase + sr)*(J*DIN);
  f32x4v ld[8];

  auto issue = [&](int c){
    const f32x4v* src = (const f32x4v*)(frow + c*KC + sc*4);
    #pragma unroll
    for (int i=0;i<8;++i) ld[i] = __builtin_nontemporal_load(src + i*16);
  };
  auto writeLDS = [&](int buf){
    #pragma unroll
    for (int i=0;i<8;++i){
      ushort4 hv;
      hv.x=f2bf(ld[i].x); hv.y=f2bf(ld[i].y); hv.z=f2bf(ld[i].z); hv.w=f2bf(ld[i].w);
      const int f = sc*4 + i*64;
      *(ushort4*)&Ab[buf][(sr*KC + f) ^ ((sr&7)<<3)] = hv;
    }
  };

  issue(0); writeLDS(0);
  __syncthreads();

  const int swz = (lo&7)<<3;   // same for row lo and row 16+lo

  for (int c=0;c<NCH;++c){
    const int buf = c&1;
    if (c+1<NCH) issue(c+1);
    const int v = c>>2;
    #pragma unroll
    for (int ks=0;ks<2;++ks){
      const int kl = w*64 + ks*32 + oc*8;        // k within chunk (8 waves x 64)
      bf16x8 a0 = *(const bf16x8*)&Ab[buf][(lo*KC + kl) ^ swz];
      bf16x8 a1 = *(const bf16x8*)&Ab[buf][((16+lo)*KC + kl) ^ swz];
      const int kg8 = ((c&3)*KC + kl) >> 3;      // k-block within v
      const unsigned short* fragBase = Wp + (((size_t)v*256 + kg8)*17)*8;
      bf16x8 bA = *(const bf16x8*)(fragBase + lo*8);
      bf16x8 bB = {0,0,0,0,0,0,0,0};
      if (lo==0) bB = *(const bf16x8*)(fragBase + 16*8);
      acc00 = __builtin_amdgcn_mfma_f32_16x16x32_bf16(a0, bA, acc00, 0,0,0);
      acc10 = __builtin_amdgcn_mfma_f32_16x16x32_bf16(a1, bA, acc10, 0,0,0);
      acc01 = __builtin_amdgcn_mfma_f32_16x16x32_bf16(a0, bB, acc01, 0,0,0);
      acc11 = __builtin_amdgcn_mfma_f32_16x16x32_bf16(a1, bB, acc11, 0,0,0);
    }
    if ((c&3)==3){
      // ---- v complete: two-pass cross-wave reduce + epilogue (rows 0-15, then 16-31)
      #pragma unroll
      for (int pass=0; pass<2; ++pass){
        #pragma unroll
        for (int r=0;r<4;++r){
          red[w][0][(oc*4+r)*16+lo] = pass ? acc10[r] : acc00[r];
          red[w][1][(oc*4+r)*16+lo] = pass ? acc11[r] : acc01[r];
        }
        __syncthreads();
        if (tid < 256){
          const int er = tid>>4, ec = tid&15;    // row within tile, col
          const int ri = er*16+ec;
          float h0 = red[0][0][ri]+red[1][0][ri]+red[2][0][ri]+red[3][0][ri]
                   + red[4][0][ri]+red[5][0][ri]+red[6][0][ri]+red[7][0][ri]
                   + b0[v*J+ec];
          const int row = rowBase + pass*16 + er;
          C[(size_t)row*VO + v*J + ec] = h0;
          float s0 = h0, q0 = h0*h0;
          float s1 = 0.f, q1 = 0.f;
          if (ec==0){
            const int r2 = er*16;
            float h1 = red[0][1][r2]+red[1][1][r2]+red[2][1][r2]+red[3][1][r2]
                     + red[4][1][r2]+red[5][1][r2]+red[6][1][r2]+red[7][1][r2]
                     + b0[v*J+16];
            C[(size_t)row*VO + v*J + 16] = h1;
            s1 = h1; q1 = h1*h1;
          }
          s0 += __shfl_xor(s0,16); s0 += __shfl_xor(s0,32);
          q0 += __shfl_xor(q0,16); q0 += __shfl_xor(q0,32);
          s1 += __shfl_xor(s1,16); s1 += __shfl_xor(s1,32);
          q1 += __shfl_xor(q1,16); q1 += __shfl_xor(q1,32);
          if (l < 16){ atomicAdd(&bS[v*J+l], s0); atomicAdd(&bQ[v*J+l], q0); }
          if (l == 0){ atomicAdd(&bS[v*J+16], s1); atomicAdd(&bQ[v*J+16], q1); }
        }
        __syncthreads();
      }
      acc00 = (f32x4){0.f,0.f,0.f,0.f};
      acc01 = (f32x4){0.f,0.f,0.f,0.f};
      acc10 = (f32x4){0.f,0.f,0.f,0.f};
      acc11 = (f32x4){0.f,0.f,0.f,0.f};
    }
    if (c+1<NCH){
      writeLDS(buf^1);
      __syncthreads();
    }
  }

  __syncthreads();
  const int rep = blockIdx.x & 7;
  for (int i=tid;i<VO;i+=512){
    atomicAdd(&stat0[rep*512+i],        bS[i]);
    atomicAdd(&stat0[4096 + rep*512+i], bQ[i]);
  }
}

// -------- chain: BN_j (8-replica stats) -> bitmask adjacency -> ReLU [-> resid/F]
//          [-> conv_{j+1} (transposed W, 2-row pairing) -> replica stats]   [round-4 verbatim]
template<int RESID,int WRITEF,int CONV>
__global__ __launch_bounds__(256) void chain_kernel(
  const float* __restrict__ Cin, float* __restrict__ Cout,
  float* __restrict__ F,
  const float* __restrict__ statJ,
  const float* __restrict__ g, const float* __restrict__ be,
  const float* __restrict__ Wc, const float* __restrict__ bc,
  float* __restrict__ statN)
{
  __shared__ float wsmT[J*J*JP];      // [v][o][d], d-contiguous
  __shared__ float bb[VO];
  __shared__ float aC[VO], cC[VO];
  __shared__ float hbX[4][2][J*JP];   // per-wave, 2 rows, [vertex][chan] padded
  __shared__ float ssum[VO], ssq[VO];
  const int tid = threadIdx.x, wv = tid>>6, lane = tid&63;

  if (CONV) {
    for (int i=tid;i<J*J*J;i+=256) {
      int v = i/VO, rem = i - v*VO, d = rem/J, o = rem - d*J;
      wsmT[(v*J+o)*JP + d] = Wc[i];
    }
    for (int i=tid;i<VO;i+=256) bb[i]=bc[i];
  }
  for (int i=tid;i<VO;i+=256) {
    float s=0.f,q=0.f;
    #pragma unroll
    for (int r=0;r<8;++r){ s += statJ[r*512+i]; q += statJ[4096 + r*512+i]; }
    float mu  = s*(1.f/NB);
    float var = q*(1.f/NB) - mu*mu;
    float rs  = rsqrtf(var + EPSB);
    float A = rs*g[i];
    aC[i]=A; cC[i]=be[i]-mu*A;
    ssum[i]=0.f; ssq[i]=0.f;
  }
  __syncthreads();

  float sl[5]={0,0,0,0,0}, ql[5]={0,0,0,0,0};

  #pragma unroll
  for (int it=0; it<2; ++it) {
    const int r0 = blockIdx.x*16 + wv*4 + it*2;   // rows r0, r0+1
    const float* c0 = Cin + (size_t)r0*VO;
    const float* c1 = c0 + VO;

    #pragma unroll
    for (int s=0;s<5;++s) {
      int vo = lane + 64*s;
      if (vo<VO) {
        int vtx = vo/J, o = vo - vtx*J;
        hbX[wv][0][vtx*JP+o] = c0[vo]*aC[vo] + cC[vo];
        hbX[wv][1][vtx*JP+o] = c1[vo]*aC[vo] + cC[vo];
      }
    }
    asm volatile("s_waitcnt lgkmcnt(0)" ::: "memory");

    float n0[5], n1[5];
    #pragma unroll
    for (int s=0;s<5;++s) {
      int vo = lane + 64*s;
      n0[s]=0.f; n1[s]=0.f;
      if (vo<VO) {
        int vtx = vo/J, o = vo - vtx*J;
        unsigned m = ADJM[vtx];
        float a0=0.f, a1=0.f;
        while (m) {
          int u = __ffs(m) - 1; m &= m-1;
          a0 += hbX[wv][0][u*JP+o];
          a1 += hbX[wv][1][u*JP+o];
        }
        a0 = a0>0.f?a0:0.f; a1 = a1>0.f?a1:0.f;
        size_t gi = (size_t)r0*VO + vo;
        if (RESID)  { a0 += F[gi]; a1 += F[gi+VO]; }
        if (WRITEF) { F[gi]=a0;    F[gi+VO]=a1; }
        n0[s]=a0; n1[s]=a1;
        if (!CONV) { Cout[gi]=a0; Cout[gi+VO]=a1; }
      }
    }

    if (CONV) {
      #pragma unroll
      for (int s=0;s<5;++s) {
        int vo = lane + 64*s;
        if (vo<VO) {
          int vtx = vo/J, o = vo - vtx*J;
          hbX[wv][0][vtx*JP+o] = n0[s];
          hbX[wv][1][vtx*JP+o] = n1[s];
        }
      }
      asm volatile("s_waitcnt lgkmcnt(0)" ::: "memory");
      #pragma unroll
      for (int s=0;s<5;++s) {
        int vo = lane + 64*s;
        if (vo<VO) {
          int vtx = vo/J, o = vo - vtx*J;
          const float* wp = &wsmT[(vtx*J+o)*JP];
          const float* h0 = &hbX[wv][0][vtx*JP];
          const float* h1 = &hbX[wv][1][vtx*JP];
          float a0 = bb[vo], a1 = a0;
          #pragma unroll
          for (int d=0;d<J;++d) {
            float w = wp[d];
            a0 += h0[d]*w; a1 += h1[d]*w;
          }
          size_t gi = (size_t)r0*VO + vo;
          Cout[gi]=a0; Cout[gi+VO]=a1;
          sl[s] += a0+a1; ql[s] += a0*a0 + a1*a1;
        }
      }
      asm volatile("s_waitcnt lgkmcnt(0)" ::: "memory");
    } else {
      asm volatile("s_waitcnt lgkmcnt(0)" ::: "memory");
    }
  }

  if (CONV) {
    #pragma unroll
    for (int s=0;s<5;++s) {
      int vo = lane + 64*s;
      if (vo<VO) { atomicAdd(&ssum[vo], sl[s]); atomicAdd(&ssq[vo], ql[s]); }
    }
    __syncthreads();
    const int rep = blockIdx.x & 7;
    for (int i=tid;i<VO;i+=256) {
      atomicAdd(&statN[rep*512+i],        ssum[i]);
      atomicAdd(&statN[4096 + rep*512+i], ssq[i]);
    }
  }
}

extern "C" void kernel_launch(void* const* d_in, const int* in_sizes, int n_in,
                              void* d_out, int out_size, void* d_ws, size_t ws_size,
                              hipStream_t stream)
{
  (void)in_sizes; (void)n_in; (void)out_size; (void)ws_size;
  const float* img = (const float*)d_in[0];
  const float* W0  = (const float*)d_in[1];
  const float* b0  = (const float*)d_in[2];
  const float* g0  = (const float*)d_in[3];
  const float* be0 = (const float*)d_in[4];
  const float* Wr  = (const float*)d_in[5];
  const float* br  = (const float*)d_in[6];
  const float* gr  = (const float*)d_in[7];
  const float* ber = (const float*)d_in[8];

  float* ws = (float*)d_ws;
  // stats: 9 stages x 8192 floats (8 replicas x 512 sum, then 8 x 512 sumsq)
  float* ST = ws;                              // 73728 floats
  unsigned short* Wp = (unsigned short*)(ws + 73728);    // 17*256*17*8 = 591872 ushorts
  float* Ca = ws + 73728 + 300000;
  float* Cb = Ca + (size_t)NB*VO;
  float* F  = Cb + (size_t)NB*VO;
  float* out = (float*)d_out;

  zero_stats<<<72,256,0,stream>>>(ST, 9*8192);
  wconv_kernel<<<136,256,0,stream>>>(W0, Wp);

  conv0_kernel<<<256,512,0,stream>>>(img, Wp, b0, Ca, ST);

  const int W1 = J*J*J;
  #define STG(j) (ST + (j)*8192)
  chain_kernel<0,1,1><<<512,256,0,stream>>>(Ca, Cb, F, STG(0), g0,      be0,
                                            Wr+0*W1, br+0*VO, STG(1));
  chain_kernel<0,0,1><<<512,256,0,stream>>>(Cb, Ca, F, STG(1), gr+0*VO, ber+0*VO,
                                            Wr+1*W1, br+1*VO, STG(2));
  chain_kernel<1,1,1><<<512,256,0,stream>>>(Ca, Cb, F, STG(2), gr+1*VO, ber+1*VO,
                                            Wr+2*W1, br+2*VO, STG(3));
  chain_kernel<0,0,1><<<512,256,0,stream>>>(Cb, Ca, F, STG(3), gr+2*VO, ber+2*VO,
                                            Wr+3*W1, br+3*VO, STG(4));
  chain_kernel<1,1,1><<<512,256,0,stream>>>(Ca, Cb, F, STG(4), gr+3*VO, ber+3*VO,
                                            Wr+4*W1, br+4*VO, STG(5));
  chain_kernel<0,0,1><<<512,256,0,stream>>>(Cb, Ca, F, STG(5), gr+4*VO, ber+4*VO,
                                            Wr+5*W1, br+5*VO, STG(6));
  chain_kernel<1,1,1><<<512,256,0,stream>>>(Ca, Cb, F, STG(6), gr+5*VO, ber+5*VO,
                                            Wr+6*W1, br+6*VO, STG(7));
  chain_kernel<0,0,1><<<512,256,0,stream>>>(Cb, Ca, F, STG(7), gr+6*VO, ber+6*VO,
                                            Wr+7*W1, br+7*VO, STG(8));
  chain_kernel<1,0,0><<<512,256,0,stream>>>(Ca, out, F, STG(8), gr+7*VO, ber+7*VO,
                                            nullptr, nullptr, nullptr);
  #undef STG
}